// Round 9
// baseline (786.576 us; speedup 1.0000x reference)
//
#include <hip/hip_runtime.h>
#include <hip/hip_cooperative_groups.h>
#include <cstdint>

namespace cg = cooperative_groups;

// Problem constants (from reference): B=4, Z=32, Y=512, X=512, R=1, C=16
static constexpr int Z_ = 32, Y_ = 512, X_ = 512;
static constexpr int ROW_WORDS = X_ / 32;                  // 16 u32 words per (b,z,y) row
static constexpr size_t NVOX = 4ull * Z_ * Y_ * X_;        // 33,554,432 voxels (2^25)
static constexpr size_t BITMAP_WORDS = NVOX / 32;          // 1M words = 4 MiB
static constexpr size_t BITMAP_BYTES = BITMAP_WORDS * 4;
static constexpr uint32_t REC_SENTINEL = 0xFFFFFFFFu;      // packed < 2^26, so invalid

// ws layout:
//   [0, 256)         : acc[0..3] at 64B stride (occ, off, feat, cnt)
//   [256, +4MiB)     : RADAR occupancy bitmap (1 bit per voxel)
//   [.., +128MiB)    : records, DIRECT-MAPPED u32 per voxel:
//                      (dL1<<24)|(k<<19)|lidar_row ; REC_SENTINEL = no match.
//                      Only preset (by radar phase) at radar voxels; voxels
//                      never preset are never read -> no global init needed.

// Single cooperative kernel: 5 phases separated by grid.sync().
//  P0 zero acc+bitmap -> P1 radar scatter -> P2 lidar neighborhood scan
//  -> P3 loss + reduction -> P4 finalize.
__global__ __launch_bounds__(256, 4) void fused_all(
        const float* __restrict__ pred_feat,
        const float* __restrict__ pred_occ,
        const float* __restrict__ lidar_feat,
        const int* __restrict__ radar_idx,
        const int* __restrict__ lidar_idx,
        int Nr, int Nl,
        float* __restrict__ acc,
        uint32_t* __restrict__ bitmap,
        uint32_t* __restrict__ records,
        float* __restrict__ out) {
    cg::grid_group grid = cg::this_grid();
    const uint32_t tid = blockIdx.x * blockDim.x + threadIdx.x;
    const uint32_t nthr = gridDim.x * blockDim.x;

    // ---- Phase 0: zero acc + bitmap (contiguous from acc base) ----
    {
        uint4* zb = reinterpret_cast<uint4*>(acc);
        const uint32_t n_zero = (uint32_t)((256 + BITMAP_BYTES) / 16);
        const uint4 z = make_uint4(0u, 0u, 0u, 0u);
        for (uint32_t i = tid; i < n_zero; i += nthr) zb[i] = z;
    }
    __threadfence();
    grid.sync();

    // ---- Phase 1: radar scatter — 2 fire-and-forget stores, no read-wait ----
    for (uint32_t i = tid; i < (uint32_t)Nr; i += nthr) {
        int4 ri = reinterpret_cast<const int4*>(radar_idx)[i];
        uint32_t key = (uint32_t)(((ri.x * Z_ + ri.y) * Y_ + ri.z) * X_ + ri.w);
        records[key] = REC_SENTINEL;                     // idempotent preset
        atomicOr(&bitmap[key >> 5], 1u << (key & 31));   // presence bit
    }
    __threadfence();
    grid.sync();

    // ---- Phase 2: lidar pass — strict in-domain 27-window, direct atomicMin ----
    // k = 26 - m maps the lidar-centered window index m to the reference's
    // radar-centered offset index of delta = L - R. Lexicographic min over
    // (dL1, k, row) == reference first-occurrence argmin + min-row dup rule.
    for (uint32_t i = tid; i < (uint32_t)Nl; i += nthr) {
        int4 li = reinterpret_cast<const int4*>(lidar_idx)[i];
        const int b = li.x, z = li.y, y = li.z, x = li.w;

        const int xm1 = max(x - 1, 0);
        const int w0  = xm1 >> 5;
        const int w1  = min(w0 + 1, ROW_WORDS - 1);
        const int base = w0 << 5;

        uint32_t mask = 0;  // bit m set => radar voxel present at window offset m
        #pragma unroll
        for (int dz = -1; dz <= 1; ++dz) {
            int zz = z + dz;
            if (zz < 0 || zz >= Z_) continue;
            #pragma unroll
            for (int dy = -1; dy <= 1; ++dy) {
                int yy = y + dy;
                if (yy < 0 || yy >= Y_) continue;
                uint32_t rw = (uint32_t)((b * Z_ + zz) * Y_ + yy) * ROW_WORDS;
                uint64_t win = (uint64_t)bitmap[rw + w0] |
                               ((uint64_t)bitmap[rw + w1] << 32);
                #pragma unroll
                for (int dx = -1; dx <= 1; ++dx) {
                    int xx = x + dx;
                    if (xx < 0 || xx >= X_) continue;
                    int m = (dz + 1) * 9 + (dy + 1) * 3 + (dx + 1);
                    mask |= (uint32_t)((win >> (xx - base)) & 1ull) << m;
                }
            }
        }

        while (mask) {
            int m = __builtin_ctz(mask);
            mask &= mask - 1;
            int mdz = m / 9 - 1, mr = m % 9;
            int mdy = mr / 3 - 1, mdx = mr % 3 - 1;
            uint32_t vkey = (uint32_t)(((b * Z_ + (z + mdz)) * Y_ + (y + mdy)) * X_ + (x + mdx));
            uint32_t dl1 = (uint32_t)(abs(mdz) + abs(mdy) + abs(mdx));
            uint32_t k   = (uint32_t)(26 - m);           // k of delta = L - R
            uint32_t packed = (dl1 << 24) | (k << 19) | i;
            atomicMin(&records[vkey], packed);           // direct-mapped, no probe
        }
    }
    __threadfence();
    grid.sync();

    // ---- Phase 3: loss — direct record load, hierarchical reduction ----
    {
        float occ_a = 0.f, off_a = 0.f, feat_a = 0.f, cnt_a = 0.f;
        for (uint32_t r = tid; r < (uint32_t)Nr; r += nthr) {
            int4 ri = reinterpret_cast<const int4*>(radar_idx)[r];
            uint32_t key = (uint32_t)(((ri.x * Z_ + ri.y) * Y_ + ri.z) * X_ + ri.w);
            uint32_t rec = records[key];                 // preset in P1, maybe min'd in P2

            float o = pred_occ[r];
            float sp = fmaxf(o, 0.f) + log1pf(expf(-fabsf(o)));  // stable softplus
            bool matched = (rec != REC_SENTINEL);
            occ_a += sp - (matched ? o : 0.f);

            if (matched) {
                cnt_a += 1.f;
                int wk  = (int)((rec >> 19) & 31u);
                int row = (int)(rec & 0x7FFFFu);
                int wdz = wk / 9 - 1, wr = wk % 9;
                int wdy = wr / 3 - 1, wdx = wr % 3 - 1;
                float4 pf = reinterpret_cast<const float4*>(pred_feat)[r];
                float p[3]  = { pf.x, pf.y, pf.z };
                float gt[3] = { (float)wdz, (float)wdy, (float)wdx };
                #pragma unroll
                for (int j = 0; j < 3; ++j) {
                    float dd = p[j] - gt[j];
                    float ad = fabsf(dd);
                    off_a += (ad < 1.f) ? 0.5f * dd * dd : ad - 0.5f;
                }
                feat_a += fabsf(pf.w - lidar_feat[16 * row]);
            }
        }

        #pragma unroll
        for (int o = 32; o >= 1; o >>= 1) {
            occ_a  += __shfl_xor(occ_a,  o, 64);
            off_a  += __shfl_xor(off_a,  o, 64);
            feat_a += __shfl_xor(feat_a, o, 64);
            cnt_a  += __shfl_xor(cnt_a,  o, 64);
        }
        __shared__ float red[4][4];
        int wid = threadIdx.x >> 6;
        if ((threadIdx.x & 63) == 0) {
            red[wid][0] = occ_a; red[wid][1] = off_a;
            red[wid][2] = feat_a; red[wid][3] = cnt_a;
        }
        __syncthreads();
        if (threadIdx.x == 0) {
            float s0 = 0.f, s1 = 0.f, s2 = 0.f, s3 = 0.f;
            #pragma unroll
            for (int w = 0; w < 4; ++w) {
                s0 += red[w][0]; s1 += red[w][1]; s2 += red[w][2]; s3 += red[w][3];
            }
            atomicAdd(&acc[0],  s0);
            atomicAdd(&acc[16], s1);
            atomicAdd(&acc[32], s2);
            atomicAdd(&acc[48], s3);
        }
    }
    __threadfence();
    grid.sync();

    // ---- Phase 4: finalize ----
    if (tid == 0) {
        float occ  = acc[0] / (float)Nr;
        float cnt  = acc[48];
        float offl = acc[16] / fmaxf(cnt * 3.f, 1.f);
        float feat = acc[32] / fmaxf(cnt, 1.f);
        out[0] = 0.2f * occ + offl + feat;
    }
}

extern "C" void kernel_launch(void* const* d_in, const int* in_sizes, int n_in,
                              void* d_out, int out_size, void* d_ws, size_t ws_size,
                              hipStream_t stream) {
    const float* pred_feat  = (const float*)d_in[0];
    const float* pred_occ   = (const float*)d_in[1];
    const float* lidar_feat = (const float*)d_in[2];
    const int*   radar_idx  = (const int*)d_in[3];
    const int*   lidar_idx  = (const int*)d_in[4];
    int Nr = in_sizes[1];        // pred_occ is (Nr, 1)
    int Nl = in_sizes[2] / 16;   // lidar_features is (Nl, 16)

    float*    acc     = (float*)d_ws;
    uint32_t* bitmap  = (uint32_t*)((char*)d_ws + 256);
    uint32_t* records = (uint32_t*)((char*)d_ws + 256 + BITMAP_BYTES);  // 128 MiB direct map
    float*    out     = (float*)d_out;

    void* args[] = {
        (void*)&pred_feat, (void*)&pred_occ, (void*)&lidar_feat,
        (void*)&radar_idx, (void*)&lidar_idx,
        (void*)&Nr, (void*)&Nl,
        (void*)&acc, (void*)&bitmap, (void*)&records, (void*)&out
    };
    // 1024 blocks x 256 threads: 4 blocks/CU guaranteed co-resident
    // (launch_bounds(256,4)), all phases grid-stride.
    hipLaunchCooperativeKernel((const void*)fused_all, dim3(1024), dim3(256),
                               args, 0, stream);
}

// Round 10
// 72.492 us; speedup vs baseline: 10.8505x; 10.8505x over previous
//
#include <hip/hip_runtime.h>
#include <cstdint>

// Problem constants (from reference): B=4, Z=32, Y=512, X=512, R=1, C=16
static constexpr int Z_ = 32, Y_ = 512, X_ = 512;
static constexpr int ROW_WORDS = X_ / 32;                  // 16 u32 words per (b,z,y) row
static constexpr size_t NVOX = 4ull * Z_ * Y_ * X_;        // 33,554,432 voxels (2^25)
static constexpr size_t BITMAP_WORDS = NVOX / 32;          // 1M words = 4 MiB
static constexpr size_t BITMAP_BYTES = BITMAP_WORDS * 4;
static constexpr uint32_t REC_SENTINEL = 0xFFFFFFFFu;      // packed < 2^26, so invalid

// ws layout:
//   [0, 256)         : acc[0..3] at 64B stride (occ, off, feat, cnt)
//   [256, +4MiB)     : RADAR occupancy bitmap (1 bit per voxel)
//   [.., +128MiB)    : records, DIRECT-MAPPED u32 per voxel:
//                      (dL1<<24)|(k<<19)|lidar_row ; REC_SENTINEL = no match.
//                      Only preset (by radar_scatter) at radar voxels; voxels
//                      never preset are never read -> no global init needed.
//
// NOTE (R9 lesson): cooperative grid.sync() costs ~190us per barrier on MI355X
// (cross-XCD spin) — phase separation via separate in-stream dispatches is
// ~50x cheaper. Keep the multi-kernel pipeline.

// Fast init: rocclr fillBufferAligned runs at 8% occupancy (~42us for 4MB);
// this grid-stride uint4 kernel does acc+bitmap in ~2us.
__global__ __launch_bounds__(256) void init_kernel(uint4* __restrict__ zero_base,
                                                   uint32_t n_zero) {
    uint32_t t = blockIdx.x * blockDim.x + threadIdx.x;
    uint32_t stride = gridDim.x * blockDim.x;
    const uint4 z = make_uint4(0u, 0u, 0u, 0u);
    for (uint32_t i = t; i < n_zero; i += stride) zero_base[i] = z;
}

// Radar scatter: 2 fire-and-forget ops per point, no read-wait chains.
__global__ void radar_scatter(const int* __restrict__ radar_idx, int Nr,
                              uint32_t* __restrict__ records,
                              uint32_t* __restrict__ bitmap) {
    int i = blockIdx.x * blockDim.x + threadIdx.x;
    if (i >= Nr) return;
    int4 ri = reinterpret_cast<const int4*>(radar_idx)[i];
    uint32_t key = (uint32_t)(((ri.x * Z_ + ri.y) * Y_ + ri.z) * X_ + ri.w);
    records[key] = REC_SENTINEL;                     // idempotent preset (plain store)
    atomicOr(&bitmap[key >> 5], 1u << (key & 31));   // presence bit
}

// Lidar pass: strict in-domain 27-window over the radar bitmap, then direct
// atomicMin into records[vkey]. k = 26 - m maps the lidar-centered window
// index m to the radar-centered offset index of delta = L - R. Lexicographic
// min over (dL1, k, row) == reference first-occurrence argmin + min-row rule.
__global__ __launch_bounds__(256) void lidar_pass(
        const int* __restrict__ lidar_idx, int Nl,
        const uint32_t* __restrict__ bitmap,
        uint32_t* __restrict__ records) {
    int i = blockIdx.x * blockDim.x + threadIdx.x;
    if (i >= Nl) return;
    int4 li = reinterpret_cast<const int4*>(lidar_idx)[i];
    const int b = li.x, z = li.y, y = li.z, x = li.w;

    const int xm1 = max(x - 1, 0);
    const int w0  = xm1 >> 5;
    const int w1  = min(w0 + 1, ROW_WORDS - 1);
    const int base = w0 << 5;

    uint32_t mask = 0;  // bit m set => radar voxel present at window offset m
    #pragma unroll
    for (int dz = -1; dz <= 1; ++dz) {
        int zz = z + dz;
        if (zz < 0 || zz >= Z_) continue;
        #pragma unroll
        for (int dy = -1; dy <= 1; ++dy) {
            int yy = y + dy;
            if (yy < 0 || yy >= Y_) continue;
            uint32_t rw = (uint32_t)((b * Z_ + zz) * Y_ + yy) * ROW_WORDS;
            uint64_t win = (uint64_t)bitmap[rw + w0] |
                           ((uint64_t)bitmap[rw + w1] << 32);
            #pragma unroll
            for (int dx = -1; dx <= 1; ++dx) {
                int xx = x + dx;
                if (xx < 0 || xx >= X_) continue;
                int m = (dz + 1) * 9 + (dy + 1) * 3 + (dx + 1);
                mask |= (uint32_t)((win >> (xx - base)) & 1ull) << m;
            }
        }
    }

    while (mask) {
        int m = __builtin_ctz(mask);
        mask &= mask - 1;
        int mdz = m / 9 - 1, mr = m % 9;
        int mdy = mr / 3 - 1, mdx = mr % 3 - 1;
        uint32_t vkey = (uint32_t)(((b * Z_ + (z + mdz)) * Y_ + (y + mdy)) * X_ + (x + mdx));
        uint32_t dl1 = (uint32_t)(abs(mdz) + abs(mdy) + abs(mdx));
        uint32_t k   = (uint32_t)(26 - m);               // k of delta = L - R
        uint32_t packed = (dl1 << 24) | (k << 19) | (uint32_t)i;
        atomicMin(&records[vkey], packed);               // direct-mapped, no probe
    }
}

// Loss pass: one thread per radar point; single direct record load.
__global__ __launch_bounds__(256) void loss_pass(
        const float* __restrict__ pred_feat,
        const float* __restrict__ pred_occ,
        const float* __restrict__ lidar_feat,
        const int* __restrict__ radar_idx,
        const uint32_t* __restrict__ records,
        int Nr, float* __restrict__ acc) {
    float occ_a = 0.f, off_a = 0.f, feat_a = 0.f, cnt_a = 0.f;
    int r = blockIdx.x * blockDim.x + threadIdx.x;
    if (r < Nr) {
        int4 ri = reinterpret_cast<const int4*>(radar_idx)[r];
        uint32_t key = (uint32_t)(((ri.x * Z_ + ri.y) * Y_ + ri.z) * X_ + ri.w);
        uint32_t rec = records[key];     // preset in radar_scatter, min'd in lidar_pass

        float o = pred_occ[r];
        float sp = fmaxf(o, 0.f) + log1pf(expf(-fabsf(o)));  // stable softplus
        bool matched = (rec != REC_SENTINEL);
        occ_a = sp - (matched ? o : 0.f);

        if (matched) {
            cnt_a = 1.f;
            int wk  = (int)((rec >> 19) & 31u);
            int row = (int)(rec & 0x7FFFFu);
            int wdz = wk / 9 - 1, wr = wk % 9;
            int wdy = wr / 3 - 1, wdx = wr % 3 - 1;
            float4 pf = reinterpret_cast<const float4*>(pred_feat)[r];
            float p[3]  = { pf.x, pf.y, pf.z };
            float gt[3] = { (float)wdz, (float)wdy, (float)wdx };
            #pragma unroll
            for (int j = 0; j < 3; ++j) {
                float dd = p[j] - gt[j];
                float ad = fabsf(dd);
                off_a += (ad < 1.f) ? 0.5f * dd * dd : ad - 0.5f;
            }
            feat_a = fabsf(pf.w - lidar_feat[16 * row]);
        }
    }

    #pragma unroll
    for (int o = 32; o >= 1; o >>= 1) {
        occ_a  += __shfl_xor(occ_a,  o, 64);
        off_a  += __shfl_xor(off_a,  o, 64);
        feat_a += __shfl_xor(feat_a, o, 64);
        cnt_a  += __shfl_xor(cnt_a,  o, 64);
    }
    __shared__ float red[4][4];
    int wid = threadIdx.x >> 6;
    if ((threadIdx.x & 63) == 0) {
        red[wid][0] = occ_a; red[wid][1] = off_a;
        red[wid][2] = feat_a; red[wid][3] = cnt_a;
    }
    __syncthreads();
    if (threadIdx.x == 0) {
        float s0 = 0.f, s1 = 0.f, s2 = 0.f, s3 = 0.f;
        #pragma unroll
        for (int w = 0; w < 4; ++w) {
            s0 += red[w][0]; s1 += red[w][1]; s2 += red[w][2]; s3 += red[w][3];
        }
        atomicAdd(&acc[0],  s0);
        atomicAdd(&acc[16], s1);
        atomicAdd(&acc[32], s2);
        atomicAdd(&acc[48], s3);
    }
}

__global__ void finalize_kernel(const float* __restrict__ acc, int Nr, float* __restrict__ out) {
    float occ  = acc[0] / (float)Nr;
    float cnt  = acc[48];
    float offl = acc[16] / fmaxf(cnt * 3.f, 1.f);
    float feat = acc[32] / fmaxf(cnt, 1.f);
    out[0] = 0.2f * occ + offl + feat;
}

extern "C" void kernel_launch(void* const* d_in, const int* in_sizes, int n_in,
                              void* d_out, int out_size, void* d_ws, size_t ws_size,
                              hipStream_t stream) {
    const float* pred_feat  = (const float*)d_in[0];
    const float* pred_occ   = (const float*)d_in[1];
    const float* lidar_feat = (const float*)d_in[2];
    const int*   radar_idx  = (const int*)d_in[3];
    const int*   lidar_idx  = (const int*)d_in[4];
    int Nr = in_sizes[1];        // pred_occ is (Nr, 1)
    int Nl = in_sizes[2] / 16;   // lidar_features is (Nl, 16)

    float*    acc     = (float*)d_ws;
    uint32_t* bitmap  = (uint32_t*)((char*)d_ws + 256);
    uint32_t* records = (uint32_t*)((char*)d_ws + 256 + BITMAP_BYTES);  // 128 MiB direct map

    const uint32_t n_zero = (uint32_t)((256 + BITMAP_BYTES) / 16);      // acc + bitmap

    hipLaunchKernelGGL(init_kernel, dim3(1024), dim3(256), 0, stream,
                       (uint4*)d_ws, n_zero);
    hipLaunchKernelGGL(radar_scatter, dim3((Nr + 255) / 256), dim3(256), 0, stream,
                       radar_idx, Nr, records, bitmap);
    hipLaunchKernelGGL(lidar_pass, dim3((Nl + 255) / 256), dim3(256), 0, stream,
                       lidar_idx, Nl, bitmap, records);
    hipLaunchKernelGGL(loss_pass, dim3((Nr + 255) / 256), dim3(256), 0, stream,
                       pred_feat, pred_occ, lidar_feat, radar_idx, records, Nr, acc);
    hipLaunchKernelGGL(finalize_kernel, dim3(1), dim3(1), 0, stream, acc, Nr, (float*)d_out);
}